// Round 11
// baseline (209.046 us; speedup 1.0000x reference)
//
#include <hip/hip_runtime.h>
#include <hip/hip_bf16.h>

#define BATCH 64
#define MDIM 512
#define NDIM 1024
#define KDIM 1024

#define BM 256
#define BN 128
#define BK 32
#define NKT (KDIM / BK)     // 32 K-tiles

typedef __attribute__((ext_vector_type(4))) float f32x4;
typedef __attribute__((ext_vector_type(8))) short bf16x8;
typedef __attribute__((ext_vector_type(4))) unsigned int u32x4;

// fp32 pair -> packed bf16x2 (RNE); emits v_cvt_pk_bf16_f32
__device__ __forceinline__ unsigned int cvt2(float lo, float hi) {
    __hip_bfloat162 h = __float22bfloat162_rn(float2{lo, hi});
    return *(unsigned int*)&h;
}

#define MFMA16(a, b, c) __builtin_amdgcn_mfma_f32_16x16x32_bf16((a), (b), (c), 0, 0, 0)

// Seal per K-tile: drain OUR ds ops, raw s_barrier, sched fences (rule 18).
// NO vmcnt drain — staging global loads stay in flight across the barrier.
#define TILE_SEAL do { \
    asm volatile("s_waitcnt lgkmcnt(0)" ::: "memory"); \
    __builtin_amdgcn_sched_barrier(0); \
    __builtin_amdgcn_s_barrier(); \
    __builtin_amdgcn_sched_barrier(0); } while (0)

__global__ __launch_bounds__(512, 4)   // 4 waves/EU: unified reg budget 128
void grouped_fc_kernel(const float* __restrict__ X,
                       const float* __restrict__ W,
                       const float* __restrict__ Bias,
                       float* __restrict__ Out) {
    // XCD swizzle (bijective: 1024 % 8 == 0): XCD j gets batches [8j, 8j+8)
    const int swz  = (blockIdx.x & 7) * 128 + (blockIdx.x >> 3);
    const int bidx = swz >> 4;      // 0..63 batch
    const int tile = swz & 15;      // 2 M-tiles x 8 N-tiles
    const int tm = tile & 1;
    const int tn = tile >> 1;       // 0..7

    const int tid  = threadIdx.x;
    const int lane = tid & 63;
    const int wid  = tid >> 6;      // 0..7
    const int wm   = wid & 3;       // 4 wave rows (64 out-rows each)
    const int wn   = wid >> 2;      // 2 wave cols (64 out-cols each)

    // [row][32] bf16, 4 x 16B slots/row; slot s stored at s ^ ((row>>1)&3)
    // (R3/R6/R9-verified family: SQ_LDS_BANK_CONFLICT == 0). 48 KB total
    // -> 2 blocks/CU.
    __shared__ unsigned short ldsA[2][BM][BK];
    __shared__ unsigned short ldsB[2][BN][BK];

    const float* srcA = X + ((size_t)bidx * MDIM + (size_t)tm * BM) * KDIM;
    const float* srcB = W + ((size_t)bidx * NDIM + (size_t)tn * BN) * KDIM;

    // staging units of 8 fp32: A has 1024 units (256 rows x 4 slots),
    // thread takes {tid, tid+512}; B has 512 units (128 x 4), thread takes tid.
    const int uA0 = tid, uA1 = tid + 512, uB = tid;
    const int rA0 = uA0 >> 2, sA0 = uA0 & 3;
    const int rA1 = uA1 >> 2, sA1 = uA1 & 3;
    const int rB  = uB  >> 2, sB  = uB  & 3;
    const int wA0 = (sA0 ^ ((rA0 >> 1) & 3)) * 8;   // swizzled bf16 offsets
    const int wA1 = (sA1 ^ ((rA1 >> 1) & 3)) * 8;
    const int wB  = (sB  ^ ((rB  >> 1) & 3)) * 8;

    f32x4 fa0[2], fa1[2], fb[2];    // 24 staging VGPRs

    auto ISSUE = [&](int kt) {
        const float* p0 = srcA + (size_t)rA0 * KDIM + kt * BK + sA0 * 8;
        const float* p1 = srcA + (size_t)rA1 * KDIM + kt * BK + sA1 * 8;
        const float* pb = srcB + (size_t)rB  * KDIM + kt * BK + sB  * 8;
        fa0[0] = *(const f32x4*)(p0); fa0[1] = *(const f32x4*)(p0 + 4);
        fa1[0] = *(const f32x4*)(p1); fa1[1] = *(const f32x4*)(p1 + 4);
        fb[0]  = *(const f32x4*)(pb); fb[1]  = *(const f32x4*)(pb + 4);
    };

    auto CVTW = [&](int buf) {
        u32x4 w0, w1, w2;
        w0[0] = cvt2(fa0[0][0], fa0[0][1]); w0[1] = cvt2(fa0[0][2], fa0[0][3]);
        w0[2] = cvt2(fa0[1][0], fa0[1][1]); w0[3] = cvt2(fa0[1][2], fa0[1][3]);
        w1[0] = cvt2(fa1[0][0], fa1[0][1]); w1[1] = cvt2(fa1[0][2], fa1[0][3]);
        w1[2] = cvt2(fa1[1][0], fa1[1][1]); w1[3] = cvt2(fa1[1][2], fa1[1][3]);
        w2[0] = cvt2(fb[0][0],  fb[0][1]);  w2[1] = cvt2(fb[0][2],  fb[0][3]);
        w2[2] = cvt2(fb[1][0],  fb[1][1]);  w2[3] = cvt2(fb[1][2],  fb[1][3]);
        *(u32x4*)&ldsA[buf][rA0][wA0] = w0;
        *(u32x4*)&ldsA[buf][rA1][wA1] = w1;
        *(u32x4*)&ldsB[buf][rB][wB]   = w2;
    };

    // frag reads: frag base rows are 16-aligned, so (row>>1)&3 == (frow>>1)&3
    const int frow = lane & 15;
    const int khi  = lane >> 4;     // k-slot 0..3
    const int rsl  = (khi ^ ((frow >> 1) & 3)) * 8;

    f32x4 acc[4][4];
#pragma unroll
    for (int mi = 0; mi < 4; ++mi)
#pragma unroll
        for (int ni = 0; ni < 4; ++ni)
            acc[mi][ni] = (f32x4){0.f, 0.f, 0.f, 0.f};

    // prologue: tile 0 -> buf0
    ISSUE(0);
    CVTW(0);
    TILE_SEAL;

#pragma unroll 1
    for (int kt = 0; kt < NKT; ++kt) {
        const int rd = kt & 1;
        const bool m1 = (kt + 1 < NKT);

        // issue next tile's loads — land during frag reads + MFMA
        if (m1) ISSUE(kt + 1);

        bf16x8 af[4], bfr[4];
#pragma unroll
        for (int mi = 0; mi < 4; ++mi)
            af[mi] = *(const bf16x8*)&ldsA[rd][wm * 64 + mi * 16 + frow][rsl];
#pragma unroll
        for (int ni = 0; ni < 4; ++ni)
            bfr[ni] = *(const bf16x8*)&ldsB[rd][wn * 64 + ni * 16 + frow][rsl];

        __builtin_amdgcn_s_setprio(1);
#pragma unroll
        for (int mi = 0; mi < 4; ++mi)
#pragma unroll
            for (int ni = 0; ni < 4; ++ni)
                acc[mi][ni] = MFMA16(af[mi], bfr[ni], acc[mi][ni]);
        __builtin_amdgcn_s_setprio(0);

        // publish next tile into the other buffer
        if (m1) CVTW(rd ^ 1);

        TILE_SEAL;   // writes drained + barrier; buffers swap
    }

    // epilogue: acc layout col=lane&15, row=(lane>>4)*4+r (m89-verified)
#pragma unroll
    for (int ni = 0; ni < 4; ++ni) {
        const int gc = tn * BN + wn * 64 + ni * 16 + frow;
        const float bv = Bias[bidx * NDIM + gc];
#pragma unroll
        for (int mi = 0; mi < 4; ++mi) {
            const int gr0 = tm * BM + wm * 64 + mi * 16 + khi * 4;
            float* po = Out + ((size_t)bidx * MDIM + gr0) * NDIM + gc;
#pragma unroll
            for (int r = 0; r < 4; ++r)
                po[(size_t)r * NDIM] = acc[mi][ni][r] + bv;
        }
    }
}

extern "C" void kernel_launch(void* const* d_in, const int* in_sizes, int n_in,
                              void* d_out, int out_size, void* d_ws, size_t ws_size,
                              hipStream_t stream) {
    const float* X  = (const float*)d_in[0];
    const float* W  = (const float*)d_in[1];
    const float* Bs = (const float*)d_in[2];
    float* Out = (float*)d_out;

    grouped_fc_kernel<<<dim3(1024), dim3(512), 0, stream>>>(X, W, Bs, Out);
}

// Round 12
// 190.855 us; speedup vs baseline: 1.0953x; 1.0953x over previous
//
#include <hip/hip_runtime.h>
#include <hip/hip_bf16.h>

#define BATCH 64
#define MDIM 512
#define NDIM 1024
#define KDIM 1024

#define BM 256
#define BN 256
#define BK 32               // fp32 per row-tile (128 B = 8 x 16B granules)
#define NKT (KDIM / BK)     // 32 K-tiles

typedef __attribute__((ext_vector_type(4))) float f32x4;
typedef __attribute__((ext_vector_type(8))) short bf16x8;
typedef __attribute__((ext_vector_type(4))) unsigned int u32x4;

// fp32 pair -> packed bf16x2 (RNE); emits v_cvt_pk_bf16_f32
__device__ __forceinline__ unsigned int cvt2(float lo, float hi) {
    __hip_bfloat162 h = __float22bfloat162_rn(float2{lo, hi});
    return *(unsigned int*)&h;
}

#define MFMA16(a, b, c) __builtin_amdgcn_mfma_f32_16x16x32_bf16((a), (b), (c), 0, 0, 0)

__global__ __launch_bounds__(512, 2)
void grouped_fc_kernel(const float* __restrict__ X,
                       const float* __restrict__ W,
                       const float* __restrict__ Bias,
                       float* __restrict__ Out) {
    // XCD swizzle (bijective: 512 % 8 == 0): XCD j gets batches [8j, 8j+8)
    const int swz  = (blockIdx.x & 7) * 64 + (blockIdx.x >> 3);
    const int bidx = swz >> 3;     // 0..63 batch
    const int tile = swz & 7;      // 2 M-tiles x 4 N-tiles
    const int tm = tile & 1;
    const int tn = tile >> 1;

    const int tid  = threadIdx.x;
    const int lane = tid & 63;
    const int wid  = tid >> 6;     // 0..7
    const int wm   = wid & 1;      // 2 wave rows (128 out-rows)
    const int wn   = wid >> 1;     // 4 wave cols (64 out-cols)

    // fp32 tiles, [row][8 x 16B granules]. DMA writes LINEAR LDS; the
    // swizzle lives in the per-lane GLOBAL source address (m173 pattern):
    //   LDS[r][p] = global[r][p ^ (r&7)]
    // Frag reads then read slot (2*khi)^(r&7) -> uniform 8 lanes per slot
    // position -> conflict-free (same uniform-slot model R9 measured at 0).
    __shared__ float ldsA[2][BM][BK];
    __shared__ float ldsB[2][BN][BK];

    const float* srcA = X + ((size_t)bidx * MDIM + (size_t)tm * BM) * KDIM;
    const float* srcB = W + ((size_t)bidx * NDIM + (size_t)tn * BN) * KDIM;

    // DMA geometry: one instr = 64 lanes x 16B = 1 KB = 8 fp32 rows.
    // lane l covers row-in-chunk (l>>3), source granule (l&7)^(l>>3).
    const int lrow = lane >> 3;              // 0..7
    const int lgr  = (lane & 7) ^ lrow;      // pre-swizzled source granule
    const size_t lsrc = (size_t)lrow * KDIM + lgr * 4;  // fp32 offset

    auto STAGE = [&](int buf, int kt) {      // 8 global_load_lds per thread
#pragma unroll
        for (int j = 0; j < 4; ++j) {
            const int c = wid * 4 + j;       // chunk 0..31 (8 rows each)
            const float* ga = srcA + (size_t)c * 8 * KDIM + kt * BK + lsrc;
            __builtin_amdgcn_global_load_lds(
                (const __attribute__((address_space(1))) void*)ga,
                (__attribute__((address_space(3))) void*)&ldsA[buf][c * 8][0],
                16, 0, 0);
        }
#pragma unroll
        for (int j = 0; j < 4; ++j) {
            const int c = wid * 4 + j;
            const float* gb = srcB + (size_t)c * 8 * KDIM + kt * BK + lsrc;
            __builtin_amdgcn_global_load_lds(
                (const __attribute__((address_space(1))) void*)gb,
                (__attribute__((address_space(3))) void*)&ldsB[buf][c * 8][0],
                16, 0, 0);
        }
    };

    // frag reads: lane (frow, khi) needs K fp32 [khi*8, khi*8+8) of its row
    // = global granules {2khi, 2khi+1} = LDS slots {(2khi)^(r&7), ^1}.
    // r&7 == frow&7 (frag base rows are multiples of 16).
    const int frow = lane & 15;
    const int khi  = lane >> 4;
    const int s0   = (((khi * 2) ^ (frow & 7))) * 4;  // fp32 offset, granule0

    auto RDFRAG = [&](const float* rowp) -> bf16x8 {
        f32x4 lo = *(const f32x4*)(rowp + s0);        // K khi*8 .. +4
        f32x4 hi = *(const f32x4*)(rowp + (s0 ^ 4));  // K khi*8+4 .. +8
        u32x4 u;
        u[0] = cvt2(lo[0], lo[1]); u[1] = cvt2(lo[2], lo[3]);
        u[2] = cvt2(hi[0], hi[1]); u[3] = cvt2(hi[2], hi[3]);
        return __builtin_bit_cast(bf16x8, u);
    };

    f32x4 acc[8][4];
#pragma unroll
    for (int mi = 0; mi < 8; ++mi)
#pragma unroll
        for (int ni = 0; ni < 4; ++ni)
            acc[mi][ni] = (f32x4){0.f, 0.f, 0.f, 0.f};

    // prologue: DMA tile 0 -> buf0, drain, seal
    STAGE(0, 0);
    asm volatile("s_waitcnt vmcnt(0)" ::: "memory");
    __builtin_amdgcn_sched_barrier(0);
    __builtin_amdgcn_s_barrier();
    __builtin_amdgcn_sched_barrier(0);

#pragma unroll 1
    for (int kt = 0; kt < NKT; ++kt) {
        const int rd = kt & 1;
        const bool m1 = (kt + 1 < NKT);

        // issue next tile's DMA first — flies across this tile's compute
        if (m1) STAGE(rd ^ 1, kt + 1);

        bf16x8 af[8], bfr[4];
#pragma unroll
        for (int mi = 0; mi < 8; ++mi)
            af[mi] = RDFRAG(&ldsA[rd][wm * 128 + mi * 16 + frow][0]);
#pragma unroll
        for (int ni = 0; ni < 4; ++ni)
            bfr[ni] = RDFRAG(&ldsB[rd][wn * 64 + ni * 16 + frow][0]);

        __builtin_amdgcn_s_setprio(1);
#pragma unroll
        for (int mi = 0; mi < 8; ++mi)
#pragma unroll
            for (int ni = 0; ni < 4; ++ni)
                acc[mi][ni] = MFMA16(af[mi], bfr[ni], acc[mi][ni]);
        __builtin_amdgcn_s_setprio(0);

        // seal: my DMA for kt+1 landed (vmcnt counts global_load_lds);
        // no ds_writes exist, and my ds_reads were consumed by the MFMAs.
        asm volatile("s_waitcnt vmcnt(0)" ::: "memory");
        __builtin_amdgcn_sched_barrier(0);
        __builtin_amdgcn_s_barrier();
        __builtin_amdgcn_sched_barrier(0);
    }

    // epilogue: acc layout col=lane&15, row=(lane>>4)*4+r (m89-verified)
#pragma unroll
    for (int ni = 0; ni < 4; ++ni) {
        const int gc = tn * BN + wn * 64 + ni * 16 + frow;
        const float bv = Bias[bidx * NDIM + gc];
#pragma unroll
        for (int mi = 0; mi < 8; ++mi) {
            const int gr0 = tm * BM + wm * 128 + mi * 16 + khi * 4;
            float* po = Out + ((size_t)bidx * MDIM + gr0) * NDIM + gc;
#pragma unroll
            for (int r = 0; r < 4; ++r)
                po[(size_t)r * NDIM] = acc[mi][ni][r] + bv;
        }
    }
}

extern "C" void kernel_launch(void* const* d_in, const int* in_sizes, int n_in,
                              void* d_out, int out_size, void* d_ws, size_t ws_size,
                              hipStream_t stream) {
    const float* X  = (const float*)d_in[0];
    const float* W  = (const float*)d_in[1];
    const float* Bs = (const float*)d_in[2];
    float* Out = (float*)d_out;

    grouped_fc_kernel<<<dim3(512), dim3(512), 0, stream>>>(X, W, Bs, Out);
}

// Round 16
// 138.486 us; speedup vs baseline: 1.5095x; 1.3782x over previous
//
#include <hip/hip_runtime.h>
#include <hip/hip_bf16.h>

#define BATCH 64
#define MDIM 512
#define NDIM 1024
#define KDIM 1024

#define BM 256
#define BN 256
#define BK 64
#define NKT (KDIM / BK)     // 16 K-tiles

typedef __attribute__((ext_vector_type(4))) float f32x4;
typedef __attribute__((ext_vector_type(8))) short bf16x8;
typedef __attribute__((ext_vector_type(4))) unsigned int u32x4;

__device__ __forceinline__ unsigned int cvt2(float lo, float hi) {
    __hip_bfloat162 h = __float22bfloat162_rn(float2{lo, hi});
    return *(unsigned int*)&h;
}

#define MFMA16(a, b, c) __builtin_amdgcn_mfma_f32_16x16x32_bf16((a), (b), (c), 0, 0, 0)
#define SB0 __builtin_amdgcn_sched_barrier(0)
// counted lgkm wait (T4 for the DS queue): DS ops complete in-order, so
// waiting to N leaves the N NEWEST ops (our writes) pending while all older
// frag reads are complete. sched_barrier right after (rule 18).
#define WAITLG(n) do { asm volatile("s_waitcnt lgkmcnt(" #n ")" ::: "memory"); SB0; } while (0)
#define BAR do { SB0; __builtin_amdgcn_s_barrier(); SB0; } while (0)

__global__ __launch_bounds__(512, 2)
void grouped_fc_kernel(const float* __restrict__ X,
                       const float* __restrict__ W,
                       const float* __restrict__ Bias,
                       float* __restrict__ Out) {
    // XCD swizzle (bijective: 512 % 8 == 0)
    const int swz  = (blockIdx.x & 7) * 64 + (blockIdx.x >> 3);
    const int bidx = swz >> 3;
    const int tile = swz & 7;
    const int tm = tile & 1;
    const int tn = tile >> 1;

    const int tid  = threadIdx.x;
    const int lane = tid & 63;
    const int wid  = tid >> 6;
    const int wm   = wid & 1;      // 2 wave rows (128 out-rows)
    const int wn   = wid >> 1;     // 4 wave cols (64 out-cols)

    // [row][64] bf16 = 8 x 16B slots/row; slot s at s ^ (row&7).
    // R9-verified: SQ_LDS_BANK_CONFLICT == 0.
    __shared__ unsigned short ldsA[2][BM][BK];
    __shared__ unsigned short ldsB[2][BN][BK];

    const float* srcA = X + ((size_t)bidx * MDIM + (size_t)tm * BM) * KDIM;
    const float* srcB = W + ((size_t)bidx * NDIM + (size_t)tn * BN) * KDIM;

    // staging: 4 threads/row, 16 fp32 each, per 128-row half-tile
    const int s_r  = tid >> 2;
    const int s_cf = (tid & 3) * 16;
    const int s_x  = s_r & 7;
    const int so0  = (((tid & 3) * 2)     ^ s_x) * 8;
    const int so1  = (((tid & 3) * 2 + 1) ^ s_x) * 8;

    f32x4 st0[4], st1[4];

    auto ISSUE = [&](const float* srcbase, int hv, int kt_, f32x4 (&s)[4]) {
        const float* p = srcbase + (size_t)(hv * 128 + s_r) * KDIM + kt_ * BK + s_cf;
#pragma unroll
        for (int v = 0; v < 4; ++v) s[v] = *(const f32x4*)(p + v * 4);
    };

    auto CVTW = [&](unsigned short* ldsbase, int hv, f32x4 (&s)[4]) {
        const int row = hv * 128 + s_r;
        u32x4 w0, w1;
        w0[0] = cvt2(s[0][0], s[0][1]); w0[1] = cvt2(s[0][2], s[0][3]);
        w0[2] = cvt2(s[1][0], s[1][1]); w0[3] = cvt2(s[1][2], s[1][3]);
        w1[0] = cvt2(s[2][0], s[2][1]); w1[1] = cvt2(s[2][2], s[2][3]);
        w1[2] = cvt2(s[3][0], s[3][1]); w1[3] = cvt2(s[3][2], s[3][3]);
        *(u32x4*)&ldsbase[(size_t)row * BK + so0] = w0;
        *(u32x4*)&ldsbase[(size_t)row * BK + so1] = w1;
    };

    // frag reads: row&7 == frow&7 (frag base rows are multiples of 8)
    const int frow = lane & 15;
    const int khi  = lane >> 4;
    const int xr   = frow & 7;
    const int oK0  = ((khi)     ^ xr) * 8;
    const int oK1  = ((4 + khi) ^ xr) * 8;

    auto rdA = [&](int buf, int mi, int o) {
        return *(const bf16x8*)&ldsA[buf][wm * 128 + mi * 16 + frow][o];
    };
    auto rdB = [&](int buf, int ni, int o) {
        return *(const bf16x8*)&ldsB[buf][wn * 64 + ni * 16 + frow][o];
    };

    f32x4 acc[8][4];
#pragma unroll
    for (int mi = 0; mi < 8; ++mi)
#pragma unroll
        for (int ni = 0; ni < 4; ++ni)
            acc[mi][ni] = (f32x4){0.f, 0.f, 0.f, 0.f};

    // ---- prologue: stage tile 0 -> buf0; issue tile-1 A halves ----
    ISSUE(srcA, 0, 0, st0); ISSUE(srcA, 1, 0, st1);
    CVTW(&ldsA[0][0][0], 0, st0); CVTW(&ldsA[0][0][0], 1, st1);
    ISSUE(srcB, 0, 0, st0); ISSUE(srcB, 1, 0, st1);
    CVTW(&ldsB[0][0][0], 0, st0); CVTW(&ldsB[0][0][0], 1, st1);
    ISSUE(srcA, 0, 1, st0); ISSUE(srcA, 1, 1, st1);
    WAITLG(0);
    BAR;

    bf16x8 af[8], bfr[4];

    // main loop: tiles 0..NKT-2 (always stage tile kt+1); 4 phases, ONE
    // barrier each. DS order per phase: [MFMA] -> reads(next phase) ->
    // writes(next tile) -> bar. Counted WAITLG leaves only writes pending.
#pragma unroll 1
    for (int kt = 0; kt < NKT - 1; ++kt) {
        const int rd = kt & 1;
        const bool m2 = (kt + 2 < NKT);
        unsigned short* nA = &ldsA[rd ^ 1][0][0];
        unsigned short* nB = &ldsB[rd ^ 1][0][0];

        // ---- P0: fresh buffer — must read after seal (exposed once/tile)
#pragma unroll
        for (int mi = 0; mi < 8; ++mi) af[mi] = rdA(rd, mi, oK0);
        bfr[0] = rdB(rd, 0, oK0); bfr[1] = rdB(rd, 1, oK0);
        WAITLG(0);
        __builtin_amdgcn_s_setprio(1);
#pragma unroll
        for (int mi = 0; mi < 8; ++mi) {
            acc[mi][0] = MFMA16(af[mi], bfr[0], acc[mi][0]);
            acc[mi][1] = MFMA16(af[mi], bfr[1], acc[mi][1]);
        }
        __builtin_amdgcn_s_setprio(0);
        SB0;
        bfr[2] = rdB(rd, 2, oK0); bfr[3] = rdB(rd, 3, oK0);   // 2 reads
        CVTW(nA, 0, st0);                                      // 2 writes
        ISSUE(srcB, 0, kt + 1, st0);                           // vmcnt only
        BAR;

        // ---- P1: queue [r2, w2] -> wait 2 => reads done, writes fly
        WAITLG(2);
        __builtin_amdgcn_s_setprio(1);
#pragma unroll
        for (int mi = 0; mi < 8; ++mi) {
            acc[mi][2] = MFMA16(af[mi], bfr[2], acc[mi][2]);
            acc[mi][3] = MFMA16(af[mi], bfr[3], acc[mi][3]);
        }
        __builtin_amdgcn_s_setprio(0);
        SB0;
#pragma unroll
        for (int mi = 0; mi < 8; ++mi) af[mi] = rdA(rd, mi, oK1);  // 8 reads
        bfr[0] = rdB(rd, 0, oK1); bfr[1] = rdB(rd, 1, oK1);        // 2 reads
        CVTW(nA, 1, st1);                                          // 2 writes
        ISSUE(srcB, 1, kt + 1, st1);
        BAR;

        // ---- P2: queue [w2, r10, w2] -> wait 2 => all reads done
        WAITLG(2);
        __builtin_amdgcn_s_setprio(1);
#pragma unroll
        for (int mi = 0; mi < 8; ++mi) {
            acc[mi][0] = MFMA16(af[mi], bfr[0], acc[mi][0]);
            acc[mi][1] = MFMA16(af[mi], bfr[1], acc[mi][1]);
        }
        __builtin_amdgcn_s_setprio(0);
        SB0;
        bfr[2] = rdB(rd, 2, oK1); bfr[3] = rdB(rd, 3, oK1);   // 2 reads
        CVTW(nB, 0, st0);                                      // 2 writes
        if (m2) ISSUE(srcA, 0, kt + 2, st0);
        BAR;

        // ---- P3: queue [w2, r2, w2] -> wait 2 => reads done
        WAITLG(2);
        __builtin_amdgcn_s_setprio(1);
#pragma unroll
        for (int mi = 0; mi < 8; ++mi) {
            acc[mi][2] = MFMA16(af[mi], bfr[2], acc[mi][2]);
            acc[mi][3] = MFMA16(af[mi], bfr[3], acc[mi][3]);
        }
        __builtin_amdgcn_s_setprio(0);
        SB0;
        CVTW(nB, 1, st1);                                      // 2 writes
        if (m2) ISSUE(srcA, 1, kt + 2, st1);
        WAITLG(0);                                             // tile seal drain
        BAR;                                                   // buf^1 sealed
    }

    // ---- peeled last tile (no staging) ----
    {
        const int rd = (NKT - 1) & 1;
#pragma unroll
        for (int mi = 0; mi < 8; ++mi) af[mi] = rdA(rd, mi, oK0);
#pragma unroll
        for (int ni = 0; ni < 4; ++ni) bfr[ni] = rdB(rd, ni, oK0);
        WAITLG(0);
#pragma unroll
        for (int mi = 0; mi < 8; ++mi)
#pragma unroll
            for (int ni = 0; ni < 4; ++ni)
                acc[mi][ni] = MFMA16(af[mi], bfr[ni], acc[mi][ni]);
#pragma unroll
        for (int mi = 0; mi < 8; ++mi) af[mi] = rdA(rd, mi, oK1);
#pragma unroll
        for (int ni = 0; ni < 4; ++ni) bfr[ni] = rdB(rd, ni, oK1);
        WAITLG(0);
#pragma unroll
        for (int mi = 0; mi < 8; ++mi)
#pragma unroll
            for (int ni = 0; ni < 4; ++ni)
                acc[mi][ni] = MFMA16(af[mi], bfr[ni], acc[mi][ni]);
    }

    // epilogue: acc layout col=lane&15, row=(lane>>4)*4+r (m89-verified)
#pragma unroll
    for (int ni = 0; ni < 4; ++ni) {
        const int gc = tn * BN + wn * 64 + ni * 16 + frow;
        const float bv = Bias[bidx * NDIM + gc];
#pragma unroll
        for (int mi = 0; mi < 8; ++mi) {
            const int gr0 = tm * BM + wm * 128 + mi * 16 + khi * 4;
            float* po = Out + ((size_t)bidx * MDIM + gr0) * NDIM + gc;
#pragma unroll
            for (int r = 0; r < 4; ++r)
                po[(size_t)r * NDIM] = acc[mi][ni][r] + bv;
        }
    }
}

extern "C" void kernel_launch(void* const* d_in, const int* in_sizes, int n_in,
                              void* d_out, int out_size, void* d_ws, size_t ws_size,
                              hipStream_t stream) {
    const float* X  = (const float*)d_in[0];
    const float* W  = (const float*)d_in[1];
    const float* Bs = (const float*)d_in[2];
    float* Out = (float*)d_out;

    grouped_fc_kernel<<<dim3(512), dim3(512), 0, stream>>>(X, W, Bs, Out);
}